// Round 13
// baseline (362.495 us; speedup 1.0000x reference)
//
#include <hip/hip_runtime.h>
#include <stdint.h>

// Batch-hard triplet loss, N=8192, D=128, fp32 input.
// R13: R12 (barrier-free, LDS-free, direct-L2 B-frags, 1-wave blocks) with
// three latency fixes, counter-driven (R12: MfmaUtil 13.8 & VALUBusy 24.9
// both low, occ 18.4% = 2 waves/SIMD -> latency-bound):
//  1) JSPLIT 16->32: 4096 blocks -> 3-4 waves/SIMD offered; (64,3) keeps
//     the allocator at R12's measured ~160-reg footprint (96V + AGPRs).
//     Bonus: bid%8 == s%8 -> per-XCD L2 holds only 4 B-strips + A (2.25MB).
//  2) strip labels preloaded/packed (4 ints) -> no per-step label loads.
//  3) sched_barrier(0) after B-prefetch issue -> compiler can't sink the
//     loads to their use site (the "prefetch" was decorative in R12).

#define NROWS 8192
#define DIM 128
#define MARGIN_F 0.3f

typedef float f32x4 __attribute__((ext_vector_type(4)));
typedef short s16x8 __attribute__((ext_vector_type(8)));
typedef unsigned short u16x8 __attribute__((ext_vector_type(8)));

__device__ __forceinline__ unsigned short bf16rn(float x) {
  union { float f; uint32_t u; } v; v.f = x;
  uint32_t r = v.u + 0x7FFFu + ((v.u >> 16) & 1u);
  return (unsigned short)(r >> 16);
}

// ---------------- split pre-pass: E fp32 -> bf16 ----------------
__global__ __launch_bounds__(256) void tl_split(const float* __restrict__ E,
                                                unsigned short* __restrict__ hi) {
  const int idx = blockIdx.x * 256 + threadIdx.x;  // 131072 threads x 8 elems
  const float4 f0 = ((const float4*)E)[2 * idx];
  const float4 f1 = ((const float4*)E)[2 * idx + 1];
  float f[8] = {f0.x, f0.y, f0.z, f0.w, f1.x, f1.y, f1.z, f1.w};
  u16x8 h;
#pragma unroll
  for (int i = 0; i < 8; ++i) h[i] = bf16rn(f[i]);
  ((u16x8*)hi)[idx] = h;
}

// ---------------- main MFMA kernel: 1 wave per block ----------------
#define JSPLIT3 32
#define JRANGE3 (NROWS / JSPLIT3)  // 256
#define CSTEP 32
#define NSTEPS (JRANGE3 / CSTEP)   // 8
#define WROWS 64
#define NRB3 (NROWS / WROWS)       // 128 -> grid 4096 waves

__global__ __launch_bounds__(64, 3) void tl_mfma(
    const unsigned short* __restrict__ Ehi, const int* __restrict__ labels,
    float* __restrict__ part) {
  const int l = threadIdx.x;       // 0..63
  const int lq = l >> 4;           // 0..3
  const int lr = l & 15;           // 0..15
  const int bid = blockIdx.x;
  const int s = bid & (JSPLIT3 - 1);
  const int rb = bid >> 5;         // 0..127
  const int row0 = rb * WROWS;
  const int jbase0 = s * JRANGE3;

  // label element-size probe (int64 vs int32): odd 32-bit words all zero
  bool odd0 = true;
  const int4* lp4 = (const int4*)labels;
#pragma unroll
  for (int q = 0; q < 8; ++q) {
    int4 v = lp4[q];
    odd0 = odd0 && (v.y == 0) && (v.w == 0);
  }
  const int lstride = odd0 ? 2 : 1;

  // packed row labels: byte j of rlabp[mi] = label(row0+mi*16+lq*4+j)
  int rlabp[4];
#pragma unroll
  for (int mi = 0; mi < 4; ++mi) {
    int v = 0;
#pragma unroll
    for (int j = 0; j < 4; ++j)
      v |= labels[(row0 + mi * 16 + lq * 4 + j) * lstride] << (8 * j);
    rlabp[mi] = v;
  }

  // packed strip-column labels: idx = st*2+ni (0..15) -> clp[idx>>2] byte idx&3
  // col(st,ni) = jbase0 + st*CSTEP + ni*16 + lr
  int clp[4];
#pragma unroll
  for (int w = 0; w < 4; ++w) {
    int v = 0;
#pragma unroll
    for (int b = 0; b < 4; ++b) {
      const int idx = w * 4 + b;
      const int st = idx >> 1, ni = idx & 1;
      v |= labels[(jbase0 + st * CSTEP + ni * 16 + lr) * lstride] << (8 * b);
    }
    clp[w] = v;
  }

  // A fragments (64 regs), pinned so the allocator can't rematerialize the
  // global loads inside the step loop (R6 failure mode).
  s16x8 ahf[4][4];  // [ks][mi]
#pragma unroll
  for (int ks = 0; ks < 4; ++ks)
#pragma unroll
    for (int mi = 0; mi < 4; ++mi) {
      const size_t off =
          (size_t)(row0 + mi * 16 + lr) * DIM + (ks * 4 + lq) * 8;
      ahf[ks][mi] = *(const s16x8*)&Ehi[off];
    }
#pragma unroll
  for (int ks = 0; ks < 4; ++ks)
#pragma unroll
    for (int mi = 0; mi < 4; ++mi)
      asm volatile("" : "+v"(ahf[ks][mi]));

  float minS[16], maxD[16];
#pragma unroll
  for (int i = 0; i < 16; ++i) { minS[i] = 1e30f; maxD[i] = -1e30f; }

  // B-fragment loader: 8 x s16x8; per instruction the wave reads 16 rows x
  // 64B contiguous (line-coalesced, L2-resident).
  s16x8 b0[8], b1[8];
  auto loadB = [&](s16x8 (&b)[8], int step) {
    const int jb = jbase0 + step * CSTEP;
#pragma unroll
    for (int ni = 0; ni < 2; ++ni)
#pragma unroll
      for (int ks = 0; ks < 4; ++ks) {
        const size_t off =
            (size_t)(jb + ni * 16 + lr) * DIM + (ks * 4 + lq) * 8;
        b[ni * 4 + ks] = *(const s16x8*)&Ehi[off];
      }
  };

  auto doStep = [&](s16x8 (&bc)[8], s16x8 (&bn)[8], int step) {
    if (step + 1 < NSTEPS) {
      loadB(bn, step + 1);  // prefetch next into regs
      __builtin_amdgcn_sched_barrier(0);  // pin the issue point (don't sink)
    }

    f32x4 acc[4][2];
#pragma unroll
    for (int mi = 0; mi < 4; ++mi)
#pragma unroll
      for (int ni = 0; ni < 2; ++ni) acc[mi][ni] = (f32x4){0.f, 0.f, 0.f, 0.f};

#pragma unroll
    for (int ni = 0; ni < 2; ++ni)
#pragma unroll
      for (int ks = 0; ks < 4; ++ks)
#pragma unroll
        for (int mi = 0; mi < 4; ++mi)
          acc[mi][ni] = __builtin_amdgcn_mfma_f32_16x16x32_bf16(
              ahf[ks][mi], bc[ni * 4 + ks], acc[mi][ni], 0, 0, 0);

    // fused epilogue: running min(dot|same) / max(dot|diff); labels from
    // the preloaded packed regs (static indices after unroll).
#pragma unroll
    for (int ni = 0; ni < 2; ++ni) {
      const int cidx = step * 2 + ni;
      const int cl = (clp[cidx >> 2] >> (8 * (cidx & 3))) & 255;
#pragma unroll
      for (int mi = 0; mi < 4; ++mi)
#pragma unroll
        for (int j = 0; j < 4; ++j) {
          const int rl = (rlabp[mi] >> (8 * j)) & 255;
          const int idx = mi * 4 + j;
          const float d = acc[mi][ni][j];
          const bool same = (cl == rl);
          minS[idx] = (same && d < minS[idx]) ? d : minS[idx];
          maxD[idx] = (!same && d > maxD[idx]) ? d : maxD[idx];
        }
    }
  };

  loadB(b0, 0);
#pragma unroll
  for (int st = 0; st < NSTEPS; st += 2) {
    doStep(b0, b1, st);
    doStep(b1, b0, st + 1);
  }

  // reduce across the 16 lanes (cols) sharing each row
#pragma unroll
  for (int i = 0; i < 16; ++i) {
    float v0 = minS[i], v1 = maxD[i];
#pragma unroll
    for (int off = 1; off < 16; off <<= 1) {
      v0 = fminf(v0, __shfl_xor(v0, off));
      v1 = fmaxf(v1, __shfl_xor(v1, off));
    }
    minS[i] = v0; maxD[i] = v1;
  }
  if (lr == 0) {
#pragma unroll
    for (int mi = 0; mi < 4; ++mi)
#pragma unroll
      for (int j = 0; j < 4; ++j) {
        const int row = row0 + mi * 16 + lq * 4 + j;
        part[(size_t)s * NROWS + row] = minS[mi * 4 + j];
        part[(size_t)(JSPLIT3 + s) * NROWS + row] = maxD[mi * 4 + j];
      }
  }
}

// ---------------- 2-stage final reduce ----------------
__global__ __launch_bounds__(256) void tl_reduce_a(const float* __restrict__ part,
                                                   float* __restrict__ partial) {
  __shared__ float red[256];
  const int t = threadIdx.x;
  const int row = blockIdx.x * 256 + t;  // 32 blocks x 256 rows
  float ms = 1e30f, md = -1e30f;
#pragma unroll
  for (int s2 = 0; s2 < JSPLIT3; ++s2) {
    ms = fminf(ms, part[(size_t)s2 * NROWS + row]);
    md = fmaxf(md, part[(size_t)(JSPLIT3 + s2) * NROWS + row]);
  }
  const float hp = fmaxf(1.0f - ms, 0.0f);
  const float hn = 1.0f - md;
  red[t] = fmaxf(MARGIN_F + hp - hn, 0.0f);
  __syncthreads();
  for (int off = 128; off > 0; off >>= 1) {
    if (t < off) red[t] += red[t + off];
    __syncthreads();
  }
  if (t == 0) partial[blockIdx.x] = red[0];
}

__global__ void tl_reduce_b(const float* __restrict__ partial,
                            float* __restrict__ out) {
  const int t = threadIdx.x;  // 64 threads
  float v = (t < 32) ? partial[t] : 0.f;
#pragma unroll
  for (int off = 1; off < 64; off <<= 1) v += __shfl_xor(v, off);
  if (t == 0) out[0] = v / (float)NROWS;
}

// ================= fallback (R2-style, proven): used if ws too small =========
#define FJSPLIT 4
#define FJRANGE (NROWS / FJSPLIT)
#define FBM 128
#define FBN 64
#define FNRB (NROWS / FBM)
#define FNT (FJRANGE / FBN)

__device__ __forceinline__ float bf16tof_fb(unsigned short h) {
  union { uint32_t u; float f; } v; v.u = ((uint32_t)h) << 16;
  return v.f;
}
__device__ __forceinline__ void cvt8_fb(const float4 a, const float4 b,
                                        u16x8* h, u16x8* l) {
  float f[8] = {a.x, a.y, a.z, a.w, b.x, b.y, b.z, b.w};
  u16x8 hh, ll;
#pragma unroll
  for (int i = 0; i < 8; ++i) {
    unsigned short hv = bf16rn(f[i]);
    hh[i] = hv;
    ll[i] = bf16rn(f[i] - bf16tof_fb(hv));
  }
  *h = hh; *l = ll;
}

__global__ __launch_bounds__(256, 1) void tl_partial_fb(
    const float* __restrict__ E, const int* __restrict__ labels,
    float* __restrict__ ws) {
  __shared__ unsigned short Ah[FBM * DIM];
  __shared__ unsigned short Al[FBM * DIM];
  __shared__ unsigned short Bhs[2][FBN * DIM];
  __shared__ unsigned short Bls[2][FBN * DIM];
  __shared__ float redmin[2][FBM];
  __shared__ float redmax[2][FBM];

  const int t = threadIdx.x;
  const int l = t & 63;
  const int wid = t >> 6;
  const int wr = wid >> 1, wc = wid & 1;
  const int bid = blockIdx.x;
  const int rb = bid & (FNRB - 1);
  const int s = bid >> 6;
  const int row0 = rb * FBM;
  const int jbase0 = s * FJRANGE;

  bool odd0 = true;
  for (int q = 1; q < 128; q += 2) odd0 = odd0 && (labels[q] == 0);
  const int lstride = odd0 ? 2 : 1;

  int rlab[16];
#pragma unroll
  for (int mi = 0; mi < 4; ++mi)
#pragma unroll
    for (int j = 0; j < 4; ++j)
      rlab[mi * 4 + j] =
          labels[(row0 + wr * 64 + mi * 16 + (l >> 4) * 4 + j) * lstride];

#pragma unroll
  for (int it = 0; it < 8; ++it) {
    int gidx = it * 256 + t;
    int row = gidx >> 4;
    int kg = gidx & 15;
    const float* p = &E[(size_t)(row0 + row) * DIM + kg * 8];
    float4 f0 = *(const float4*)p;
    float4 f1 = *(const float4*)(p + 4);
    u16x8 h, lo;
    cvt8_fb(f0, f1, &h, &lo);
    int off = row * DIM + (kg ^ (row & 7)) * 8;
    *(u16x8*)&Ah[off] = h;
    *(u16x8*)&Al[off] = lo;
  }

  float4 bre[8];
  auto loadB = [&](int jt) {
#pragma unroll
    for (int it = 0; it < 4; ++it) {
      int gidx = it * 256 + t;
      int row = gidx >> 4;
      int kg = gidx & 15;
      const float* p = &E[(size_t)(jbase0 + jt * FBN + row) * DIM + kg * 8];
      bre[2 * it] = *(const float4*)p;
      bre[2 * it + 1] = *(const float4*)(p + 4);
    }
  };
  auto writeB = [&](int buf) {
#pragma unroll
    for (int it = 0; it < 4; ++it) {
      int gidx = it * 256 + t;
      int row = gidx >> 4;
      int kg = gidx & 15;
      u16x8 h, lo;
      cvt8_fb(bre[2 * it], bre[2 * it + 1], &h, &lo);
      int off = row * DIM + (kg ^ (row & 7)) * 8;
      *(u16x8*)&Bhs[buf][off] = h;
      *(u16x8*)&Bls[buf][off] = lo;
    }
  };

  loadB(0);
  writeB(0);
  __syncthreads();

  float minS[16], maxD[16];
#pragma unroll
  for (int i = 0; i < 16; ++i) { minS[i] = 1e30f; maxD[i] = -1e30f; }

  for (int jt = 0; jt < FNT; ++jt) {
    const int buf = jt & 1;
    if (jt + 1 < FNT) loadB(jt + 1);

    f32x4 acc[4][2];
#pragma unroll
    for (int mi = 0; mi < 4; ++mi)
#pragma unroll
      for (int ni = 0; ni < 2; ++ni) acc[mi][ni] = (f32x4){0.f, 0.f, 0.f, 0.f};

#pragma unroll
    for (int ks = 0; ks < 4; ++ks) {
      const int kq = ks * 4 + (l >> 4);
      s16x8 ah[4], al4[4], bh2[2], bl2[2];
#pragma unroll
      for (int mi = 0; mi < 4; ++mi) {
        int row = wr * 64 + mi * 16 + (l & 15);
        int off = row * DIM + (kq ^ (row & 7)) * 8;
        ah[mi] = *(const s16x8*)&Ah[off];
        al4[mi] = *(const s16x8*)&Al[off];
      }
#pragma unroll
      for (int ni = 0; ni < 2; ++ni) {
        int row = wc * 32 + ni * 16 + (l & 15);
        int off = row * DIM + (kq ^ (row & 7)) * 8;
        bh2[ni] = *(const s16x8*)&Bhs[buf][off];
        bl2[ni] = *(const s16x8*)&Bls[buf][off];
      }
#pragma unroll
      for (int mi = 0; mi < 4; ++mi)
#pragma unroll
        for (int ni = 0; ni < 2; ++ni) {
          acc[mi][ni] = __builtin_amdgcn_mfma_f32_16x16x32_bf16(
              ah[mi], bh2[ni], acc[mi][ni], 0, 0, 0);
          acc[mi][ni] = __builtin_amdgcn_mfma_f32_16x16x32_bf16(
              ah[mi], bl2[ni], acc[mi][ni], 0, 0, 0);
          acc[mi][ni] = __builtin_amdgcn_mfma_f32_16x16x32_bf16(
              al4[mi], bh2[ni], acc[mi][ni], 0, 0, 0);
        }
    }

    int clab[2];
#pragma unroll
    for (int ni = 0; ni < 2; ++ni)
      clab[ni] =
          labels[(jbase0 + jt * FBN + wc * 32 + ni * 16 + (l & 15)) * lstride];
#pragma unroll
    for (int mi = 0; mi < 4; ++mi)
#pragma unroll
      for (int j = 0; j < 4; ++j) {
        const int idx = mi * 4 + j;
#pragma unroll
        for (int ni = 0; ni < 2; ++ni) {
          float d = acc[mi][ni][j];
          bool same = (clab[ni] == rlab[idx]);
          minS[idx] = (same && d < minS[idx]) ? d : minS[idx];
          maxD[idx] = (!same && d > maxD[idx]) ? d : maxD[idx];
        }
      }

    if (jt + 1 < FNT) writeB(buf ^ 1);
    __syncthreads();
  }

#pragma unroll
  for (int i = 0; i < 16; ++i) {
    float v0 = minS[i], v1 = maxD[i];
#pragma unroll
    for (int off = 1; off < 16; off <<= 1) {
      v0 = fminf(v0, __shfl_xor(v0, off));
      v1 = fmaxf(v1, __shfl_xor(v1, off));
    }
    minS[i] = v0; maxD[i] = v1;
  }
  if ((l & 15) == 0) {
#pragma unroll
    for (int mi = 0; mi < 4; ++mi)
#pragma unroll
      for (int j = 0; j < 4; ++j) {
        int row = wr * 64 + mi * 16 + (l >> 4) * 4 + j;
        redmin[wc][row] = minS[mi * 4 + j];
        redmax[wc][row] = maxD[mi * 4 + j];
      }
  }
  __syncthreads();
  if (t < FBM) {
    float m = fminf(redmin[0][t], redmin[1][t]);
    float M = fmaxf(redmax[0][t], redmax[1][t]);
    ws[s * NROWS + row0 + t] = m;
    ws[(FJSPLIT + s) * NROWS + row0 + t] = M;
  }
}

__global__ void tl_reduce_fb(const float* __restrict__ ws, float* __restrict__ out) {
  __shared__ float red[256];
  const int t = threadIdx.x;
  float sum = 0.f;
  for (int r = t; r < NROWS; r += 256) {
    float ms = 1e30f, md = -1e30f;
#pragma unroll
    for (int s2 = 0; s2 < FJSPLIT; ++s2) {
      ms = fminf(ms, ws[s2 * NROWS + r]);
      md = fmaxf(md, ws[(FJSPLIT + s2) * NROWS + r]);
    }
    const float hp = fmaxf(1.0f - ms, 0.0f);
    const float hn = 1.0f - md;
    sum += fmaxf(MARGIN_F + hp - hn, 0.0f);
  }
  red[t] = sum;
  __syncthreads();
  for (int off = 128; off > 0; off >>= 1) {
    if (t < off) red[t] += red[t + off];
    __syncthreads();
  }
  if (t == 0) out[0] = red[0] / (float)NROWS;
}

extern "C" void kernel_launch(void* const* d_in, const int* in_sizes, int n_in,
                              void* d_out, int out_size, void* d_ws, size_t ws_size,
                              hipStream_t stream) {
  const float* E = (const float*)d_in[0];
  const int* labels = (const int*)d_in[1];
  float* out = (float*)d_out;

  const size_t HALF = (size_t)NROWS * DIM;       // 1048576 elems
  const size_t partOff = HALF * 2;               // 2MB (Ehi bf16)
  const size_t partElems = (size_t)2 * JSPLIT3 * NROWS;  // 2MB of partials
  const size_t need = partOff + partElems * 4 + 4096;

  if (ws_size >= need) {
    unsigned short* Ehi = (unsigned short*)d_ws;
    float* part = (float*)((char*)d_ws + partOff);
    float* partial = part + partElems;
    hipLaunchKernelGGL(tl_split, dim3(512), dim3(256), 0, stream, E, Ehi);
    hipLaunchKernelGGL(tl_mfma, dim3(NRB3 * JSPLIT3), dim3(64), 0, stream,
                       Ehi, labels, part);
    hipLaunchKernelGGL(tl_reduce_a, dim3(32), dim3(256), 0, stream, part, partial);
    hipLaunchKernelGGL(tl_reduce_b, dim3(1), dim3(64), 0, stream, partial, out);
  } else {
    float* ws = (float*)d_ws;
    hipLaunchKernelGGL(tl_partial_fb, dim3(FNRB * FJSPLIT), dim3(256), 0, stream,
                       E, labels, ws);
    hipLaunchKernelGGL(tl_reduce_fb, dim3(1), dim3(256), 0, stream, ws, out);
  }
}

// Round 14
// 164.655 us; speedup vs baseline: 2.2015x; 2.2015x over previous
//
#include <hip/hip_runtime.h>
#include <stdint.h>

// Batch-hard triplet loss, N=8192, D=128, fp32 input.
// R14: R12's proven operating point (barrier-free, LDS-free, direct-L2
// B-frags, 1-wave blocks, launch_bounds(64,2): 96 VGPR + AGPRs, no spills)
// + R13's three latency fixes re-applied WITHOUT touching the register
// budget (R13's (64,3) cut budget to ~170 -> b0/b1 spilled -> 341MB scratch
// writes, 390us):
//  1) JSPLIT 16->32: grid 4096 one-wave blocks -> 16 waves/CU offered;
//     at the ~160-reg footprint hardware fits 3 waves/SIMD (480<=512).
//  2) strip labels preloaded/packed (clp, 4 ints) -> no per-step label loads.
//  3) sched_barrier(0) after B-prefetch issue -> loads can't sink.

#define NROWS 8192
#define DIM 128
#define MARGIN_F 0.3f

typedef float f32x4 __attribute__((ext_vector_type(4)));
typedef short s16x8 __attribute__((ext_vector_type(8)));
typedef unsigned short u16x8 __attribute__((ext_vector_type(8)));

__device__ __forceinline__ unsigned short bf16rn(float x) {
  union { float f; uint32_t u; } v; v.f = x;
  uint32_t r = v.u + 0x7FFFu + ((v.u >> 16) & 1u);
  return (unsigned short)(r >> 16);
}

// ---------------- split pre-pass: E fp32 -> bf16 ----------------
__global__ __launch_bounds__(256) void tl_split(const float* __restrict__ E,
                                                unsigned short* __restrict__ hi) {
  const int idx = blockIdx.x * 256 + threadIdx.x;  // 131072 threads x 8 elems
  const float4 f0 = ((const float4*)E)[2 * idx];
  const float4 f1 = ((const float4*)E)[2 * idx + 1];
  float f[8] = {f0.x, f0.y, f0.z, f0.w, f1.x, f1.y, f1.z, f1.w};
  u16x8 h;
#pragma unroll
  for (int i = 0; i < 8; ++i) h[i] = bf16rn(f[i]);
  ((u16x8*)hi)[idx] = h;
}

// ---------------- main MFMA kernel: 1 wave per block ----------------
#define JSPLIT3 32
#define JRANGE3 (NROWS / JSPLIT3)  // 256
#define CSTEP 32
#define NSTEPS (JRANGE3 / CSTEP)   // 8
#define WROWS 64
#define NRB3 (NROWS / WROWS)       // 128 -> grid 4096 waves

__global__ __launch_bounds__(64, 2) void tl_mfma(
    const unsigned short* __restrict__ Ehi, const int* __restrict__ labels,
    float* __restrict__ part) {
  const int l = threadIdx.x;       // 0..63
  const int lq = l >> 4;           // 0..3
  const int lr = l & 15;           // 0..15
  const int bid = blockIdx.x;
  const int s = bid & (JSPLIT3 - 1);
  const int rb = bid >> 5;         // 0..127
  const int row0 = rb * WROWS;
  const int jbase0 = s * JRANGE3;

  // label element-size probe (int64 vs int32): odd 32-bit words all zero
  bool odd0 = true;
  const int4* lp4 = (const int4*)labels;
#pragma unroll
  for (int q = 0; q < 8; ++q) {
    int4 v = lp4[q];
    odd0 = odd0 && (v.y == 0) && (v.w == 0);
  }
  const int lstride = odd0 ? 2 : 1;

  // packed row labels: byte j of rlabp[mi] = label(row0+mi*16+lq*4+j)
  int rlabp[4];
#pragma unroll
  for (int mi = 0; mi < 4; ++mi) {
    int v = 0;
#pragma unroll
    for (int j = 0; j < 4; ++j)
      v |= labels[(row0 + mi * 16 + lq * 4 + j) * lstride] << (8 * j);
    rlabp[mi] = v;
  }

  // packed strip-column labels: idx = st*2+ni (0..15) -> clp[idx>>2] byte idx&3
  // col(st,ni) = jbase0 + st*CSTEP + ni*16 + lr
  int clp[4];
#pragma unroll
  for (int w = 0; w < 4; ++w) {
    int v = 0;
#pragma unroll
    for (int b = 0; b < 4; ++b) {
      const int idx = w * 4 + b;
      const int st = idx >> 1, ni = idx & 1;
      v |= labels[(jbase0 + st * CSTEP + ni * 16 + lr) * lstride] << (8 * b);
    }
    clp[w] = v;
  }

  // A fragments (64 regs), pinned so the allocator can't rematerialize the
  // global loads inside the step loop (R6 failure mode).
  s16x8 ahf[4][4];  // [ks][mi]
#pragma unroll
  for (int ks = 0; ks < 4; ++ks)
#pragma unroll
    for (int mi = 0; mi < 4; ++mi) {
      const size_t off =
          (size_t)(row0 + mi * 16 + lr) * DIM + (ks * 4 + lq) * 8;
      ahf[ks][mi] = *(const s16x8*)&Ehi[off];
    }
#pragma unroll
  for (int ks = 0; ks < 4; ++ks)
#pragma unroll
    for (int mi = 0; mi < 4; ++mi)
      asm volatile("" : "+v"(ahf[ks][mi]));

  float minS[16], maxD[16];
#pragma unroll
  for (int i = 0; i < 16; ++i) { minS[i] = 1e30f; maxD[i] = -1e30f; }

  // B-fragment loader: 8 x s16x8; per instruction the wave reads 16 rows x
  // 64B contiguous (line-coalesced, L2-resident).
  s16x8 b0[8], b1[8];
  auto loadB = [&](s16x8 (&b)[8], int step) {
    const int jb = jbase0 + step * CSTEP;
#pragma unroll
    for (int ni = 0; ni < 2; ++ni)
#pragma unroll
      for (int ks = 0; ks < 4; ++ks) {
        const size_t off =
            (size_t)(jb + ni * 16 + lr) * DIM + (ks * 4 + lq) * 8;
        b[ni * 4 + ks] = *(const s16x8*)&Ehi[off];
      }
  };

  auto doStep = [&](s16x8 (&bc)[8], s16x8 (&bn)[8], int step) {
    if (step + 1 < NSTEPS) {
      loadB(bn, step + 1);                // prefetch next into regs
      __builtin_amdgcn_sched_barrier(0);  // pin the issue point
    }

    f32x4 acc[4][2];
#pragma unroll
    for (int mi = 0; mi < 4; ++mi)
#pragma unroll
      for (int ni = 0; ni < 2; ++ni) acc[mi][ni] = (f32x4){0.f, 0.f, 0.f, 0.f};

#pragma unroll
    for (int ni = 0; ni < 2; ++ni)
#pragma unroll
      for (int ks = 0; ks < 4; ++ks)
#pragma unroll
        for (int mi = 0; mi < 4; ++mi)
          acc[mi][ni] = __builtin_amdgcn_mfma_f32_16x16x32_bf16(
              ahf[ks][mi], bc[ni * 4 + ks], acc[mi][ni], 0, 0, 0);

    // fused epilogue: running min(dot|same) / max(dot|diff); labels from
    // the preloaded packed regs (static indices after unroll).
#pragma unroll
    for (int ni = 0; ni < 2; ++ni) {
      const int cidx = step * 2 + ni;
      const int cl = (clp[cidx >> 2] >> (8 * (cidx & 3))) & 255;
#pragma unroll
      for (int mi = 0; mi < 4; ++mi)
#pragma unroll
        for (int j = 0; j < 4; ++j) {
          const int rl = (rlabp[mi] >> (8 * j)) & 255;
          const int idx = mi * 4 + j;
          const float d = acc[mi][ni][j];
          const bool same = (cl == rl);
          minS[idx] = (same && d < minS[idx]) ? d : minS[idx];
          maxD[idx] = (!same && d > maxD[idx]) ? d : maxD[idx];
        }
    }
  };

  loadB(b0, 0);
#pragma unroll
  for (int st = 0; st < NSTEPS; st += 2) {
    doStep(b0, b1, st);
    doStep(b1, b0, st + 1);
  }

  // reduce across the 16 lanes (cols) sharing each row
#pragma unroll
  for (int i = 0; i < 16; ++i) {
    float v0 = minS[i], v1 = maxD[i];
#pragma unroll
    for (int off = 1; off < 16; off <<= 1) {
      v0 = fminf(v0, __shfl_xor(v0, off));
      v1 = fmaxf(v1, __shfl_xor(v1, off));
    }
    minS[i] = v0; maxD[i] = v1;
  }
  if (lr == 0) {
#pragma unroll
    for (int mi = 0; mi < 4; ++mi)
#pragma unroll
      for (int j = 0; j < 4; ++j) {
        const int row = row0 + mi * 16 + lq * 4 + j;
        part[(size_t)s * NROWS + row] = minS[mi * 4 + j];
        part[(size_t)(JSPLIT3 + s) * NROWS + row] = maxD[mi * 4 + j];
      }
  }
}

// ---------------- 2-stage final reduce ----------------
__global__ __launch_bounds__(256) void tl_reduce_a(const float* __restrict__ part,
                                                   float* __restrict__ partial) {
  __shared__ float red[256];
  const int t = threadIdx.x;
  const int row = blockIdx.x * 256 + t;  // 32 blocks x 256 rows
  float ms = 1e30f, md = -1e30f;
#pragma unroll
  for (int s2 = 0; s2 < JSPLIT3; ++s2) {
    ms = fminf(ms, part[(size_t)s2 * NROWS + row]);
    md = fmaxf(md, part[(size_t)(JSPLIT3 + s2) * NROWS + row]);
  }
  const float hp = fmaxf(1.0f - ms, 0.0f);
  const float hn = 1.0f - md;
  red[t] = fmaxf(MARGIN_F + hp - hn, 0.0f);
  __syncthreads();
  for (int off = 128; off > 0; off >>= 1) {
    if (t < off) red[t] += red[t + off];
    __syncthreads();
  }
  if (t == 0) partial[blockIdx.x] = red[0];
}

__global__ void tl_reduce_b(const float* __restrict__ partial,
                            float* __restrict__ out) {
  const int t = threadIdx.x;  // 64 threads
  float v = (t < 32) ? partial[t] : 0.f;
#pragma unroll
  for (int off = 1; off < 64; off <<= 1) v += __shfl_xor(v, off);
  if (t == 0) out[0] = v / (float)NROWS;
}

// ================= fallback (R2-style, proven): used if ws too small =========
#define FJSPLIT 4
#define FJRANGE (NROWS / FJSPLIT)
#define FBM 128
#define FBN 64
#define FNRB (NROWS / FBM)
#define FNT (FJRANGE / FBN)

__device__ __forceinline__ float bf16tof_fb(unsigned short h) {
  union { uint32_t u; float f; } v; v.u = ((uint32_t)h) << 16;
  return v.f;
}
__device__ __forceinline__ void cvt8_fb(const float4 a, const float4 b,
                                        u16x8* h, u16x8* l) {
  float f[8] = {a.x, a.y, a.z, a.w, b.x, b.y, b.z, b.w};
  u16x8 hh, ll;
#pragma unroll
  for (int i = 0; i < 8; ++i) {
    unsigned short hv = bf16rn(f[i]);
    hh[i] = hv;
    ll[i] = bf16rn(f[i] - bf16tof_fb(hv));
  }
  *h = hh; *l = ll;
}

__global__ __launch_bounds__(256, 1) void tl_partial_fb(
    const float* __restrict__ E, const int* __restrict__ labels,
    float* __restrict__ ws) {
  __shared__ unsigned short Ah[FBM * DIM];
  __shared__ unsigned short Al[FBM * DIM];
  __shared__ unsigned short Bhs[2][FBN * DIM];
  __shared__ unsigned short Bls[2][FBN * DIM];
  __shared__ float redmin[2][FBM];
  __shared__ float redmax[2][FBM];

  const int t = threadIdx.x;
  const int l = t & 63;
  const int wid = t >> 6;
  const int wr = wid >> 1, wc = wid & 1;
  const int bid = blockIdx.x;
  const int rb = bid & (FNRB - 1);
  const int s = bid >> 6;
  const int row0 = rb * FBM;
  const int jbase0 = s * FJRANGE;

  bool odd0 = true;
  for (int q = 1; q < 128; q += 2) odd0 = odd0 && (labels[q] == 0);
  const int lstride = odd0 ? 2 : 1;

  int rlab[16];
#pragma unroll
  for (int mi = 0; mi < 4; ++mi)
#pragma unroll
    for (int j = 0; j < 4; ++j)
      rlab[mi * 4 + j] =
          labels[(row0 + wr * 64 + mi * 16 + (l >> 4) * 4 + j) * lstride];

#pragma unroll
  for (int it = 0; it < 8; ++it) {
    int gidx = it * 256 + t;
    int row = gidx >> 4;
    int kg = gidx & 15;
    const float* p = &E[(size_t)(row0 + row) * DIM + kg * 8];
    float4 f0 = *(const float4*)p;
    float4 f1 = *(const float4*)(p + 4);
    u16x8 h, lo;
    cvt8_fb(f0, f1, &h, &lo);
    int off = row * DIM + (kg ^ (row & 7)) * 8;
    *(u16x8*)&Ah[off] = h;
    *(u16x8*)&Al[off] = lo;
  }

  float4 bre[8];
  auto loadB = [&](int jt) {
#pragma unroll
    for (int it = 0; it < 4; ++it) {
      int gidx = it * 256 + t;
      int row = gidx >> 4;
      int kg = gidx & 15;
      const float* p = &E[(size_t)(jbase0 + jt * FBN + row) * DIM + kg * 8];
      bre[2 * it] = *(const float4*)p;
      bre[2 * it + 1] = *(const float4*)(p + 4);
    }
  };
  auto writeB = [&](int buf) {
#pragma unroll
    for (int it = 0; it < 4; ++it) {
      int gidx = it * 256 + t;
      int row = gidx >> 4;
      int kg = gidx & 15;
      u16x8 h, lo;
      cvt8_fb(bre[2 * it], bre[2 * it + 1], &h, &lo);
      int off = row * DIM + (kg ^ (row & 7)) * 8;
      *(u16x8*)&Bhs[buf][off] = h;
      *(u16x8*)&Bls[buf][off] = lo;
    }
  };

  loadB(0);
  writeB(0);
  __syncthreads();

  float minS[16], maxD[16];
#pragma unroll
  for (int i = 0; i < 16; ++i) { minS[i] = 1e30f; maxD[i] = -1e30f; }

  for (int jt = 0; jt < FNT; ++jt) {
    const int buf = jt & 1;
    if (jt + 1 < FNT) loadB(jt + 1);

    f32x4 acc[4][2];
#pragma unroll
    for (int mi = 0; mi < 4; ++mi)
#pragma unroll
      for (int ni = 0; ni < 2; ++ni) acc[mi][ni] = (f32x4){0.f, 0.f, 0.f, 0.f};

#pragma unroll
    for (int ks = 0; ks < 4; ++ks) {
      const int kq = ks * 4 + (l >> 4);
      s16x8 ah[4], al4[4], bh2[2], bl2[2];
#pragma unroll
      for (int mi = 0; mi < 4; ++mi) {
        int row = wr * 64 + mi * 16 + (l & 15);
        int off = row * DIM + (kq ^ (row & 7)) * 8;
        ah[mi] = *(const s16x8*)&Ah[off];
        al4[mi] = *(const s16x8*)&Al[off];
      }
#pragma unroll
      for (int ni = 0; ni < 2; ++ni) {
        int row = wc * 32 + ni * 16 + (l & 15);
        int off = row * DIM + (kq ^ (row & 7)) * 8;
        bh2[ni] = *(const s16x8*)&Bhs[buf][off];
        bl2[ni] = *(const s16x8*)&Bls[buf][off];
      }
#pragma unroll
      for (int mi = 0; mi < 4; ++mi)
#pragma unroll
        for (int ni = 0; ni < 2; ++ni) {
          acc[mi][ni] = __builtin_amdgcn_mfma_f32_16x16x32_bf16(
              ah[mi], bh2[ni], acc[mi][ni], 0, 0, 0);
          acc[mi][ni] = __builtin_amdgcn_mfma_f32_16x16x32_bf16(
              ah[mi], bl2[ni], acc[mi][ni], 0, 0, 0);
          acc[mi][ni] = __builtin_amdgcn_mfma_f32_16x16x32_bf16(
              al4[mi], bh2[ni], acc[mi][ni], 0, 0, 0);
        }
    }

    int clab[2];
#pragma unroll
    for (int ni = 0; ni < 2; ++ni)
      clab[ni] =
          labels[(jbase0 + jt * FBN + wc * 32 + ni * 16 + (l & 15)) * lstride];
#pragma unroll
    for (int mi = 0; mi < 4; ++mi)
#pragma unroll
      for (int j = 0; j < 4; ++j) {
        const int idx = mi * 4 + j;
#pragma unroll
        for (int ni = 0; ni < 2; ++ni) {
          float d = acc[mi][ni][j];
          bool same = (clab[ni] == rlab[idx]);
          minS[idx] = (same && d < minS[idx]) ? d : minS[idx];
          maxD[idx] = (!same && d > maxD[idx]) ? d : maxD[idx];
        }
      }

    if (jt + 1 < FNT) writeB(buf ^ 1);
    __syncthreads();
  }

#pragma unroll
  for (int i = 0; i < 16; ++i) {
    float v0 = minS[i], v1 = maxD[i];
#pragma unroll
    for (int off = 1; off < 16; off <<= 1) {
      v0 = fminf(v0, __shfl_xor(v0, off));
      v1 = fmaxf(v1, __shfl_xor(v1, off));
    }
    minS[i] = v0; maxD[i] = v1;
  }
  if ((l & 15) == 0) {
#pragma unroll
    for (int mi = 0; mi < 4; ++mi)
#pragma unroll
      for (int j = 0; j < 4; ++j) {
        int row = wr * 64 + mi * 16 + (l >> 4) * 4 + j;
        redmin[wc][row] = minS[mi * 4 + j];
        redmax[wc][row] = maxD[mi * 4 + j];
      }
  }
  __syncthreads();
  if (t < FBM) {
    float m = fminf(redmin[0][t], redmin[1][t]);
    float M = fmaxf(redmax[0][t], redmax[1][t]);
    ws[s * NROWS + row0 + t] = m;
    ws[(FJSPLIT + s) * NROWS + row0 + t] = M;
  }
}

__global__ void tl_reduce_fb(const float* __restrict__ ws, float* __restrict__ out) {
  __shared__ float red[256];
  const int t = threadIdx.x;
  float sum = 0.f;
  for (int r = t; r < NROWS; r += 256) {
    float ms = 1e30f, md = -1e30f;
#pragma unroll
    for (int s2 = 0; s2 < FJSPLIT; ++s2) {
      ms = fminf(ms, ws[s2 * NROWS + r]);
      md = fmaxf(md, ws[(FJSPLIT + s2) * NROWS + r]);
    }
    const float hp = fmaxf(1.0f - ms, 0.0f);
    const float hn = 1.0f - md;
    sum += fmaxf(MARGIN_F + hp - hn, 0.0f);
  }
  red[t] = sum;
  __syncthreads();
  for (int off = 128; off > 0; off >>= 1) {
    if (t < off) red[t] += red[t + off];
    __syncthreads();
  }
  if (t == 0) out[0] = red[0] / (float)NROWS;
}

extern "C" void kernel_launch(void* const* d_in, const int* in_sizes, int n_in,
                              void* d_out, int out_size, void* d_ws, size_t ws_size,
                              hipStream_t stream) {
  const float* E = (const float*)d_in[0];
  const int* labels = (const int*)d_in[1];
  float* out = (float*)d_out;

  const size_t HALF = (size_t)NROWS * DIM;       // 1048576 elems
  const size_t partOff = HALF * 2;               // 2MB (Ehi bf16)
  const size_t partElems = (size_t)2 * JSPLIT3 * NROWS;  // 2MB of partials
  const size_t need = partOff + partElems * 4 + 4096;

  if (ws_size >= need) {
    unsigned short* Ehi = (unsigned short*)d_ws;
    float* part = (float*)((char*)d_ws + partOff);
    float* partial = part + partElems;
    hipLaunchKernelGGL(tl_split, dim3(512), dim3(256), 0, stream, E, Ehi);
    hipLaunchKernelGGL(tl_mfma, dim3(NRB3 * JSPLIT3), dim3(64), 0, stream,
                       Ehi, labels, part);
    hipLaunchKernelGGL(tl_reduce_a, dim3(32), dim3(256), 0, stream, part, partial);
    hipLaunchKernelGGL(tl_reduce_b, dim3(1), dim3(64), 0, stream, partial, out);
  } else {
    float* ws = (float*)d_ws;
    hipLaunchKernelGGL(tl_partial_fb, dim3(FNRB * FJSPLIT), dim3(256), 0, stream,
                       E, labels, ws);
    hipLaunchKernelGGL(tl_reduce_fb, dim3(1), dim3(256), 0, stream, ws, out);
  }
}

// Round 15
// 44.222 us; speedup vs baseline: 8.1972x; 3.7234x over previous
//
#include <hip/hip_runtime.h>
#include <stdint.h>

// Batch-hard triplet loss, N=8192, D=128, fp32 input.
// R15: tl_mfma reverted to R11 EXACTLY (best verified: 43.0us total, 4
// blocks/CU, no spills; R12-R14's structural experiments all tripped the
// register allocator: 96->128 VGPR + 150-340MB scratch traffic).
// Only change: the two final reduce kernels are fused into one via the
// last-block pattern (atomic counter in ws, zeroed by tl_split each launch;
// device-scope threadfence for cross-XCD visibility) -- saves one launch.

#define NROWS 8192
#define DIM 128
#define MARGIN_F 0.3f

typedef float f32x4 __attribute__((ext_vector_type(4)));
typedef short s16x8 __attribute__((ext_vector_type(8)));
typedef unsigned short u16x8 __attribute__((ext_vector_type(8)));

__device__ __forceinline__ unsigned short bf16rn(float x) {
  union { float f; uint32_t u; } v; v.f = x;
  uint32_t r = v.u + 0x7FFFu + ((v.u >> 16) & 1u);
  return (unsigned short)(r >> 16);
}

// ---------------- split pre-pass: E fp32 -> bf16 (+ zero the counter) ------
__global__ __launch_bounds__(256) void tl_split(const float* __restrict__ E,
                                                unsigned short* __restrict__ hi,
                                                unsigned int* __restrict__ cnt) {
  if (blockIdx.x == 0 && threadIdx.x == 0) *cnt = 0u;
  const int idx = blockIdx.x * 256 + threadIdx.x;  // 131072 threads x 8 elems
  const float4 f0 = ((const float4*)E)[2 * idx];
  const float4 f1 = ((const float4*)E)[2 * idx + 1];
  float f[8] = {f0.x, f0.y, f0.z, f0.w, f1.x, f1.y, f1.z, f1.w};
  u16x8 h;
#pragma unroll
  for (int i = 0; i < 8; ++i) h[i] = bf16rn(f[i]);
  ((u16x8*)hi)[idx] = h;
}

// ---------------- main MFMA kernel (R11, unchanged) ----------------
// 256 threads = 4 waves in 2x2 grid. Wave tile 32 rows x 32 cols.
#define BM2 64
#define BN2 64
#define JSPLIT2 8
#define JRANGE2 (NROWS / JSPLIT2)  // 1024
#define NT2 (JRANGE2 / BN2)        // 16 tiles
#define NRB2 (NROWS / BM2)         // 128 row blocks -> grid 1024 = 4/CU

__global__ __launch_bounds__(256, 4) void tl_mfma(
    const unsigned short* __restrict__ Ehi, const int* __restrict__ labels,
    float* __restrict__ part) {
  __shared__ unsigned short Bh[2][BN2 * DIM];  // 32 KB
  __shared__ float redmin[2][BM2];             // 512 B
  __shared__ float redmax[2][BM2];             // 512 B

  const int t = threadIdx.x;
  const int l = t & 63;
  const int lq = l >> 4;           // 0..3
  const int lr = l & 15;           // 0..15
  const int wid = t >> 6;          // 0..3
  const int wr = wid >> 1;         // 0..1  (32-row group)
  const int wc = wid & 1;          // 0..1  (32-col group)
  const int s = blockIdx.x & 7;    // j-split == XCD (round-robin dispatch)
  const int rb = blockIdx.x >> 3;  // 0..127
  const int row0 = rb * BM2;
  const int jbase0 = s * JRANGE2;

  // label element-size probe (int64 vs int32): odd 32-bit words all zero
  bool odd0 = true;
  const int4* lp4 = (const int4*)labels;
#pragma unroll
  for (int q = 0; q < 8; ++q) {
    int4 v = lp4[q];
    odd0 = odd0 && (v.y == 0) && (v.w == 0);
  }
  const int lstride = odd0 ? 2 : 1;

  // packed row labels: byte j of rlabp[mi] = label(row0+wr*32+mi*16+lq*4+j)
  int rlabp[2];
#pragma unroll
  for (int mi = 0; mi < 2; ++mi) {
    int v = 0;
#pragma unroll
    for (int j = 0; j < 4; ++j)
      v |= labels[(row0 + wr * 32 + mi * 16 + lq * 4 + j) * lstride] << (8 * j);
    rlabp[mi] = v;
  }

  // A fragments straight from global (L2-resident), 32 regs, pinned "+v"
  // (R8/R10/R11-proven) so the allocator cannot rematerialize the loads.
  s16x8 ahf[4][2];  // [ks][mi]
#pragma unroll
  for (int ks = 0; ks < 4; ++ks)
#pragma unroll
    for (int mi = 0; mi < 2; ++mi) {
      const size_t off =
          (size_t)(row0 + wr * 32 + mi * 16 + lr) * DIM + (ks * 4 + lq) * 8;
      ahf[ks][mi] = *(const s16x8*)&Ehi[off];
    }
#pragma unroll
  for (int ks = 0; ks < 4; ++ks)
#pragma unroll
    for (int mi = 0; mi < 2; ++mi)
      asm volatile("" : "+v"(ahf[ks][mi]));

  // B staging: global_load_lds, linear LDS dest + inverse-swizzled source.
  // 64 rows x 16 granules = 1024 slots; 256 threads -> 4 iters.
  auto stage = [&](int jt, int buf) {
#pragma unroll
    for (int i = 0; i < 4; ++i) {
      const int g = i * 256 + t;            // granule slot 0..1023
      const int row = g >> 4;
      const int kg = (g & 15) ^ (row & 7);  // source granule (involution)
      const size_t goff = (size_t)(jbase0 + jt * BN2 + row) * DIM + kg * 8;
      __builtin_amdgcn_global_load_lds(
          (const __attribute__((address_space(1))) void*)&Ehi[goff],
          (__attribute__((address_space(3))) void*)&Bh[buf][g * 8], 16, 0, 0);
    }
  };

  float minS[8], maxD[8];
#pragma unroll
  for (int i = 0; i < 8; ++i) { minS[i] = 1e30f; maxD[i] = -1e30f; }

  stage(0, 0);
  __syncthreads();

  for (int jt = 0; jt < NT2; ++jt) {
    const int buf = jt & 1;
    if (jt + 1 < NT2) stage(jt + 1, buf ^ 1);

    int clab[2];
#pragma unroll
    for (int ni = 0; ni < 2; ++ni)
      clab[ni] = labels[(jbase0 + jt * BN2 + wc * 32 + ni * 16 + lr) * lstride];

    // keep prefetch + label loads issued above; MFMAs below
    __builtin_amdgcn_sched_barrier(0);

    f32x4 acc[2][2];
#pragma unroll
    for (int mi = 0; mi < 2; ++mi)
#pragma unroll
      for (int ni = 0; ni < 2; ++ni) acc[mi][ni] = (f32x4){0.f, 0.f, 0.f, 0.f};

#pragma unroll
    for (int ni = 0; ni < 2; ++ni) {
      const int brow = wc * 32 + ni * 16 + lr;
#pragma unroll
      for (int ks = 0; ks < 4; ++ks) {
        const int off = brow * DIM + ((ks * 4 + lq) ^ (brow & 7)) * 8;
        const s16x8 bh = *(const s16x8*)&Bh[buf][off];
#pragma unroll
        for (int mi = 0; mi < 2; ++mi)
          acc[mi][ni] = __builtin_amdgcn_mfma_f32_16x16x32_bf16(
              ahf[ks][mi], bh, acc[mi][ni], 0, 0, 0);
      }
    }

    // fused epilogue: running min(dot|same) / max(dot|diff)
#pragma unroll
    for (int mi = 0; mi < 2; ++mi)
#pragma unroll
      for (int j = 0; j < 4; ++j) {
        const int rl = (rlabp[mi] >> (8 * j)) & 255;
        const int idx = mi * 4 + j;
#pragma unroll
        for (int ni = 0; ni < 2; ++ni) {
          const float d = acc[mi][ni][j];
          const bool same = (clab[ni] == rl);
          minS[idx] = (same && d < minS[idx]) ? d : minS[idx];
          maxD[idx] = (!same && d > maxD[idx]) ? d : maxD[idx];
        }
      }
    __syncthreads();
  }

  // reduce across the 16 lanes (cols) sharing each row
#pragma unroll
  for (int i = 0; i < 8; ++i) {
    float v0 = minS[i], v1 = maxD[i];
#pragma unroll
    for (int off = 1; off < 16; off <<= 1) {
      v0 = fminf(v0, __shfl_xor(v0, off));
      v1 = fmaxf(v1, __shfl_xor(v1, off));
    }
    minS[i] = v0; maxD[i] = v1;
  }
  if (lr == 0) {
#pragma unroll
    for (int mi = 0; mi < 2; ++mi)
#pragma unroll
      for (int j = 0; j < 4; ++j) {
        const int row = wr * 32 + mi * 16 + lq * 4 + j;
        redmin[wc][row] = minS[mi * 4 + j];
        redmax[wc][row] = maxD[mi * 4 + j];
      }
  }
  __syncthreads();
  // s-major: each block writes its own contiguous 256B region per array.
  if (t < BM2) {
    const float m = fminf(redmin[0][t], redmin[1][t]);
    const float M = fmaxf(redmax[0][t], redmax[1][t]);
    part[(size_t)s * NROWS + row0 + t] = m;
    part[(size_t)(8 + s) * NROWS + row0 + t] = M;
  }
}

// ---------------- fused final reduce (last-block pattern) ----------------
__global__ __launch_bounds__(256) void tl_reduce(const float* __restrict__ part,
                                                 float* __restrict__ partial,
                                                 unsigned int* __restrict__ cnt,
                                                 float* __restrict__ out) {
  __shared__ float red[256];
  __shared__ bool last;
  const int t = threadIdx.x;
  const int row = blockIdx.x * 256 + t;  // 32 blocks x 256 rows
  float ms = 1e30f, md = -1e30f;
#pragma unroll
  for (int s2 = 0; s2 < 8; ++s2) {
    ms = fminf(ms, part[(size_t)s2 * NROWS + row]);
    md = fmaxf(md, part[(size_t)(8 + s2) * NROWS + row]);
  }
  const float hp = fmaxf(1.0f - ms, 0.0f);
  const float hn = 1.0f - md;
  red[t] = fmaxf(MARGIN_F + hp - hn, 0.0f);
  __syncthreads();
  for (int off = 128; off > 0; off >>= 1) {
    if (t < off) red[t] += red[t + off];
    __syncthreads();
  }
  if (t == 0) {
    partial[blockIdx.x] = red[0];
    __threadfence();  // device scope: cross-XCD visibility
    const unsigned int old = atomicAdd(cnt, 1u);
    last = (old == 31u);
  }
  __syncthreads();
  if (last) {
    __threadfence();
    float v = (t < 32) ? partial[t] : 0.f;
#pragma unroll
    for (int off = 1; off < 64; off <<= 1) v += __shfl_xor(v, off);
    if (t == 0) out[0] = v / (float)NROWS;
  }
}

// ================= fallback (R2-style, proven): used if ws too small =========
#define FJSPLIT 4
#define FJRANGE (NROWS / FJSPLIT)
#define FBM 128
#define FBN 64
#define FNRB (NROWS / FBM)
#define FNT (FJRANGE / FBN)

__device__ __forceinline__ float bf16tof_fb(unsigned short h) {
  union { uint32_t u; float f; } v; v.u = ((uint32_t)h) << 16;
  return v.f;
}
__device__ __forceinline__ void cvt8_fb(const float4 a, const float4 b,
                                        u16x8* h, u16x8* l) {
  float f[8] = {a.x, a.y, a.z, a.w, b.x, b.y, b.z, b.w};
  u16x8 hh, ll;
#pragma unroll
  for (int i = 0; i < 8; ++i) {
    unsigned short hv = bf16rn(f[i]);
    hh[i] = hv;
    ll[i] = bf16rn(f[i] - bf16tof_fb(hv));
  }
  *h = hh; *l = ll;
}

__global__ __launch_bounds__(256, 1) void tl_partial_fb(
    const float* __restrict__ E, const int* __restrict__ labels,
    float* __restrict__ ws) {
  __shared__ unsigned short Ah[FBM * DIM];
  __shared__ unsigned short Al[FBM * DIM];
  __shared__ unsigned short Bhs[2][FBN * DIM];
  __shared__ unsigned short Bls[2][FBN * DIM];
  __shared__ float redmin[2][FBM];
  __shared__ float redmax[2][FBM];

  const int t = threadIdx.x;
  const int l = t & 63;
  const int wid = t >> 6;
  const int wr = wid >> 1, wc = wid & 1;
  const int bid = blockIdx.x;
  const int rb = bid & (FNRB - 1);
  const int s = bid >> 6;
  const int row0 = rb * FBM;
  const int jbase0 = s * FJRANGE;

  bool odd0 = true;
  for (int q = 1; q < 128; q += 2) odd0 = odd0 && (labels[q] == 0);
  const int lstride = odd0 ? 2 : 1;

  int rlab[16];
#pragma unroll
  for (int mi = 0; mi < 4; ++mi)
#pragma unroll
    for (int j = 0; j < 4; ++j)
      rlab[mi * 4 + j] =
          labels[(row0 + wr * 64 + mi * 16 + (l >> 4) * 4 + j) * lstride];

#pragma unroll
  for (int it = 0; it < 8; ++it) {
    int gidx = it * 256 + t;
    int row = gidx >> 4;
    int kg = gidx & 15;
    const float* p = &E[(size_t)(row0 + row) * DIM + kg * 8];
    float4 f0 = *(const float4*)p;
    float4 f1 = *(const float4*)(p + 4);
    u16x8 h, lo;
    cvt8_fb(f0, f1, &h, &lo);
    int off = row * DIM + (kg ^ (row & 7)) * 8;
    *(u16x8*)&Ah[off] = h;
    *(u16x8*)&Al[off] = lo;
  }

  float4 bre[8];
  auto loadB = [&](int jt) {
#pragma unroll
    for (int it = 0; it < 4; ++it) {
      int gidx = it * 256 + t;
      int row = gidx >> 4;
      int kg = gidx & 15;
      const float* p = &E[(size_t)(jbase0 + jt * FBN + row) * DIM + kg * 8];
      bre[2 * it] = *(const float4*)p;
      bre[2 * it + 1] = *(const float4*)(p + 4);
    }
  };
  auto writeB = [&](int buf) {
#pragma unroll
    for (int it = 0; it < 4; ++it) {
      int gidx = it * 256 + t;
      int row = gidx >> 4;
      int kg = gidx & 15;
      u16x8 h, lo;
      cvt8_fb(bre[2 * it], bre[2 * it + 1], &h, &lo);
      int off = row * DIM + (kg ^ (row & 7)) * 8;
      *(u16x8*)&Bhs[buf][off] = h;
      *(u16x8*)&Bls[buf][off] = lo;
    }
  };

  loadB(0);
  writeB(0);
  __syncthreads();

  float minS[16], maxD[16];
#pragma unroll
  for (int i = 0; i < 16; ++i) { minS[i] = 1e30f; maxD[i] = -1e30f; }

  for (int jt = 0; jt < FNT; ++jt) {
    const int buf = jt & 1;
    if (jt + 1 < FNT) loadB(jt + 1);

    f32x4 acc[4][2];
#pragma unroll
    for (int mi = 0; mi < 4; ++mi)
#pragma unroll
      for (int ni = 0; ni < 2; ++ni) acc[mi][ni] = (f32x4){0.f, 0.f, 0.f, 0.f};

#pragma unroll
    for (int ks = 0; ks < 4; ++ks) {
      const int kq = ks * 4 + (l >> 4);
      s16x8 ah[4], al4[4], bh2[2], bl2[2];
#pragma unroll
      for (int mi = 0; mi < 4; ++mi) {
        int row = wr * 64 + mi * 16 + (l & 15);
        int off = row * DIM + (kq ^ (row & 7)) * 8;
        ah[mi] = *(const s16x8*)&Ah[off];
        al4[mi] = *(const s16x8*)&Al[off];
      }
#pragma unroll
      for (int ni = 0; ni < 2; ++ni) {
        int row = wc * 32 + ni * 16 + (l & 15);
        int off = row * DIM + (kq ^ (row & 7)) * 8;
        bh2[ni] = *(const s16x8*)&Bhs[buf][off];
        bl2[ni] = *(const s16x8*)&Bls[buf][off];
      }
#pragma unroll
      for (int mi = 0; mi < 4; ++mi)
#pragma unroll
        for (int ni = 0; ni < 2; ++ni) {
          acc[mi][ni] = __builtin_amdgcn_mfma_f32_16x16x32_bf16(
              ah[mi], bh2[ni], acc[mi][ni], 0, 0, 0);
          acc[mi][ni] = __builtin_amdgcn_mfma_f32_16x16x32_bf16(
              ah[mi], bl2[ni], acc[mi][ni], 0, 0, 0);
          acc[mi][ni] = __builtin_amdgcn_mfma_f32_16x16x32_bf16(
              al4[mi], bh2[ni], acc[mi][ni], 0, 0, 0);
        }
    }

    int clab[2];
#pragma unroll
    for (int ni = 0; ni < 2; ++ni)
      clab[ni] =
          labels[(jbase0 + jt * FBN + wc * 32 + ni * 16 + (l & 15)) * lstride];
#pragma unroll
    for (int mi = 0; mi < 4; ++mi)
#pragma unroll
      for (int j = 0; j < 4; ++j) {
        const int idx = mi * 4 + j;
#pragma unroll
        for (int ni = 0; ni < 2; ++ni) {
          float d = acc[mi][ni][j];
          bool same = (clab[ni] == rlab[idx]);
          minS[idx] = (same && d < minS[idx]) ? d : minS[idx];
          maxD[idx] = (!same && d > maxD[idx]) ? d : maxD[idx];
        }
      }

    if (jt + 1 < FNT) writeB(buf ^ 1);
    __syncthreads();
  }

#pragma unroll
  for (int i = 0; i < 16; ++i) {
    float v0 = minS[i], v1 = maxD[i];
#pragma unroll
    for (int off = 1; off < 16; off <<= 1) {
      v0 = fminf(v0, __shfl_xor(v0, off));
      v1 = fmaxf(v1, __shfl_xor(v1, off));
    }
    minS[i] = v0; maxD[i] = v1;
  }
  if ((l & 15) == 0) {
#pragma unroll
    for (int mi = 0; mi < 4; ++mi)
#pragma unroll
      for (int j = 0; j < 4; ++j) {
        int row = wr * 64 + mi * 16 + (l >> 4) * 4 + j;
        redmin[wc][row] = minS[mi * 4 + j];
        redmax[wc][row] = maxD[mi * 4 + j];
      }
  }
  __syncthreads();
  if (t < FBM) {
    float m = fminf(redmin[0][t], redmin[1][t]);
    float M = fmaxf(redmax[0][t], redmax[1][t]);
    ws[s * NROWS + row0 + t] = m;
    ws[(FJSPLIT + s) * NROWS + row0 + t] = M;
  }
}

__global__ void tl_reduce_fb(const float* __restrict__ ws, float* __restrict__ out) {
  __shared__ float red[256];
  const int t = threadIdx.x;
  float sum = 0.f;
  for (int r = t; r < NROWS; r += 256) {
    float ms = 1e30f, md = -1e30f;
#pragma unroll
    for (int s2 = 0; s2 < FJSPLIT; ++s2) {
      ms = fminf(ms, ws[s2 * NROWS + r]);
      md = fmaxf(md, ws[(FJSPLIT + s2) * NROWS + r]);
    }
    const float hp = fmaxf(1.0f - ms, 0.0f);
    const float hn = 1.0f - md;
    sum += fmaxf(MARGIN_F + hp - hn, 0.0f);
  }
  red[t] = sum;
  __syncthreads();
  for (int off = 128; off > 0; off >>= 1) {
    if (t < off) red[t] += red[t + off];
    __syncthreads();
  }
  if (t == 0) out[0] = red[0] / (float)NROWS;
}

extern "C" void kernel_launch(void* const* d_in, const int* in_sizes, int n_in,
                              void* d_out, int out_size, void* d_ws, size_t ws_size,
                              hipStream_t stream) {
  const float* E = (const float*)d_in[0];
  const int* labels = (const int*)d_in[1];
  float* out = (float*)d_out;

  const size_t HALF = (size_t)NROWS * DIM;       // 1048576 elems
  const size_t partOff = HALF * 2;               // 2MB (Ehi bf16)
  const size_t partBytes = (size_t)16 * NROWS * 4;  // 512KB
  const size_t need = partOff + partBytes + 4096;

  if (ws_size >= need) {
    unsigned short* Ehi = (unsigned short*)d_ws;
    float* part = (float*)((char*)d_ws + partOff);
    float* partial = (float*)((char*)d_ws + partOff + partBytes);      // 128B
    unsigned int* cnt = (unsigned int*)((char*)d_ws + partOff + partBytes + 256);
    hipLaunchKernelGGL(tl_split, dim3(512), dim3(256), 0, stream, E, Ehi, cnt);
    hipLaunchKernelGGL(tl_mfma, dim3(NRB2 * JSPLIT2), dim3(256), 0, stream,
                       Ehi, labels, part);
    hipLaunchKernelGGL(tl_reduce, dim3(32), dim3(256), 0, stream,
                       part, partial, cnt, out);
  } else {
    float* ws = (float*)d_ws;
    hipLaunchKernelGGL(tl_partial_fb, dim3(FNRB * FJSPLIT), dim3(256), 0, stream,
                       E, labels, ws);
    hipLaunchKernelGGL(tl_reduce_fb, dim3(1), dim3(256), 0, stream, ws, out);
  }
}

// Round 16
// 42.973 us; speedup vs baseline: 8.4354x; 1.0291x over previous
//
#include <hip/hip_runtime.h>
#include <stdint.h>

// Batch-hard triplet loss, N=8192, D=128, fp32 input.
// R16 == R11 exactly (session-best verified: 43.0us total).
// Pipeline: tl_split (fp32->bf16, 2MB, L2-resident) -> tl_mfma (single-term
// bf16 MFMA GEMM with fused min/max epilogue; 64x64 block tile, 4 waves,
// wave-tile 32x32, B via global_load_lds swizzled dbuf, A-frags pinned in
// regs, 4 blocks/CU) -> tl_reduce_a/b (2-stage deterministic mean).
// Numerics: threshold 1.45 on scalar mean-loss; bf16 dot error ~0.05.
// R12-R15 structural experiments (direct-L2 1-wave strips, JSPLIT/clp
// variants, fused atomic reduce) all regressed: register-allocator cliffs
// (96->128 VGPR + 150-340MB scratch) or profiling anomalies. This is the
// stable operating point.

#define NROWS 8192
#define DIM 128
#define MARGIN_F 0.3f

typedef float f32x4 __attribute__((ext_vector_type(4)));
typedef short s16x8 __attribute__((ext_vector_type(8)));
typedef unsigned short u16x8 __attribute__((ext_vector_type(8)));

__device__ __forceinline__ unsigned short bf16rn(float x) {
  union { float f; uint32_t u; } v; v.f = x;
  uint32_t r = v.u + 0x7FFFu + ((v.u >> 16) & 1u);
  return (unsigned short)(r >> 16);
}

// ---------------- split pre-pass: E fp32 -> bf16 ----------------
__global__ __launch_bounds__(256) void tl_split(const float* __restrict__ E,
                                                unsigned short* __restrict__ hi) {
  const int idx = blockIdx.x * 256 + threadIdx.x;  // 131072 threads x 8 elems
  const float4 f0 = ((const float4*)E)[2 * idx];
  const float4 f1 = ((const float4*)E)[2 * idx + 1];
  float f[8] = {f0.x, f0.y, f0.z, f0.w, f1.x, f1.y, f1.z, f1.w};
  u16x8 h;
#pragma unroll
  for (int i = 0; i < 8; ++i) h[i] = bf16rn(f[i]);
  ((u16x8*)hi)[idx] = h;
}

// ---------------- main MFMA kernel ----------------
// 256 threads = 4 waves in 2x2 grid. Wave tile 32 rows x 32 cols.
#define BM2 64
#define BN2 64
#define JSPLIT2 8
#define JRANGE2 (NROWS / JSPLIT2)  // 1024
#define NT2 (JRANGE2 / BN2)        // 16 tiles
#define NRB2 (NROWS / BM2)         // 128 row blocks -> grid 1024 = 4/CU

__global__ __launch_bounds__(256, 4) void tl_mfma(
    const unsigned short* __restrict__ Ehi, const int* __restrict__ labels,
    float* __restrict__ part) {
  __shared__ unsigned short Bh[2][BN2 * DIM];  // 32 KB
  __shared__ float redmin[2][BM2];             // 512 B
  __shared__ float redmax[2][BM2];             // 512 B

  const int t = threadIdx.x;
  const int l = t & 63;
  const int lq = l >> 4;           // 0..3
  const int lr = l & 15;           // 0..15
  const int wid = t >> 6;          // 0..3
  const int wr = wid >> 1;         // 0..1  (32-row group)
  const int wc = wid & 1;          // 0..1  (32-col group)
  const int s = blockIdx.x & 7;    // j-split == XCD (round-robin dispatch)
  const int rb = blockIdx.x >> 3;  // 0..127
  const int row0 = rb * BM2;
  const int jbase0 = s * JRANGE2;

  // label element-size probe (int64 vs int32): odd 32-bit words all zero
  bool odd0 = true;
  const int4* lp4 = (const int4*)labels;
#pragma unroll
  for (int q = 0; q < 8; ++q) {
    int4 v = lp4[q];
    odd0 = odd0 && (v.y == 0) && (v.w == 0);
  }
  const int lstride = odd0 ? 2 : 1;

  // packed row labels: byte j of rlabp[mi] = label(row0+wr*32+mi*16+lq*4+j)
  int rlabp[2];
#pragma unroll
  for (int mi = 0; mi < 2; ++mi) {
    int v = 0;
#pragma unroll
    for (int j = 0; j < 4; ++j)
      v |= labels[(row0 + wr * 32 + mi * 16 + lq * 4 + j) * lstride] << (8 * j);
    rlabp[mi] = v;
  }

  // A fragments straight from global (L2-resident), 32 regs, pinned "+v"
  // so the allocator cannot rematerialize the loads inside the tile loop.
  s16x8 ahf[4][2];  // [ks][mi]
#pragma unroll
  for (int ks = 0; ks < 4; ++ks)
#pragma unroll
    for (int mi = 0; mi < 2; ++mi) {
      const size_t off =
          (size_t)(row0 + wr * 32 + mi * 16 + lr) * DIM + (ks * 4 + lq) * 8;
      ahf[ks][mi] = *(const s16x8*)&Ehi[off];
    }
#pragma unroll
  for (int ks = 0; ks < 4; ++ks)
#pragma unroll
    for (int mi = 0; mi < 2; ++mi)
      asm volatile("" : "+v"(ahf[ks][mi]));

  // B staging: global_load_lds, linear LDS dest + inverse-swizzled source.
  // 64 rows x 16 granules = 1024 slots; 256 threads -> 4 iters.
  auto stage = [&](int jt, int buf) {
#pragma unroll
    for (int i = 0; i < 4; ++i) {
      const int g = i * 256 + t;            // granule slot 0..1023
      const int row = g >> 4;
      const int kg = (g & 15) ^ (row & 7);  // source granule (involution)
      const size_t goff = (size_t)(jbase0 + jt * BN2 + row) * DIM + kg * 8;
      __builtin_amdgcn_global_load_lds(
          (const __attribute__((address_space(1))) void*)&Ehi[goff],
          (__attribute__((address_space(3))) void*)&Bh[buf][g * 8], 16, 0, 0);
    }
  };

  float minS[8], maxD[8];
#pragma unroll
  for (int i = 0; i < 8; ++i) { minS[i] = 1e30f; maxD[i] = -1e30f; }

  stage(0, 0);
  __syncthreads();

  for (int jt = 0; jt < NT2; ++jt) {
    const int buf = jt & 1;
    if (jt + 1 < NT2) stage(jt + 1, buf ^ 1);

    int clab[2];
#pragma unroll
    for (int ni = 0; ni < 2; ++ni)
      clab[ni] = labels[(jbase0 + jt * BN2 + wc * 32 + ni * 16 + lr) * lstride];

    // keep prefetch + label loads issued above; MFMAs below
    __builtin_amdgcn_sched_barrier(0);

    f32x4 acc[2][2];
#pragma unroll
    for (int mi = 0; mi < 2; ++mi)
#pragma unroll
      for (int ni = 0; ni < 2; ++ni) acc[mi][ni] = (f32x4){0.f, 0.f, 0.f, 0.f};

#pragma unroll
    for (int ni = 0; ni < 2; ++ni) {
      const int brow = wc * 32 + ni * 16 + lr;
#pragma unroll
      for (int ks = 0; ks < 4; ++ks) {
        const int off = brow * DIM + ((ks * 4 + lq) ^ (brow & 7)) * 8;
        const s16x8 bh = *(const s16x8*)&Bh[buf][off];
#pragma unroll
        for (int mi = 0; mi < 2; ++mi)
          acc[mi][ni] = __builtin_amdgcn_mfma_f32_16x16x32_bf16(
              ahf[ks][mi], bh, acc[mi][ni], 0, 0, 0);
      }
    }

    // fused epilogue: running min(dot|same) / max(dot|diff)
#pragma unroll
    for (int mi = 0; mi < 2; ++mi)
#pragma unroll
      for (int j = 0; j < 4; ++j) {
        const int rl = (rlabp[mi] >> (8 * j)) & 255;
        const int idx = mi * 4 + j;
#pragma unroll
        for (int ni = 0; ni < 2; ++ni) {
          const float d = acc[mi][ni][j];
          const bool same = (clab[ni] == rl);
          minS[idx] = (same && d < minS[idx]) ? d : minS[idx];
          maxD[idx] = (!same && d > maxD[idx]) ? d : maxD[idx];
        }
      }
    __syncthreads();
  }

  // reduce across the 16 lanes (cols) sharing each row
#pragma unroll
  for (int i = 0; i < 8; ++i) {
    float v0 = minS[i], v1 = maxD[i];
#pragma unroll
    for (int off = 1; off < 16; off <<= 1) {
      v0 = fminf(v0, __shfl_xor(v0, off));
      v1 = fmaxf(v1, __shfl_xor(v1, off));
    }
    minS[i] = v0; maxD[i] = v1;
  }
  if (lr == 0) {
#pragma unroll
    for (int mi = 0; mi < 2; ++mi)
#pragma unroll
      for (int j = 0; j < 4; ++j) {
        const int row = wr * 32 + mi * 16 + lq * 4 + j;
        redmin[wc][row] = minS[mi * 4 + j];
        redmax[wc][row] = maxD[mi * 4 + j];
      }
  }
  __syncthreads();
  // s-major: each block writes its own contiguous 256B region per array.
  if (t < BM2) {
    const float m = fminf(redmin[0][t], redmin[1][t]);
    const float M = fmaxf(redmax[0][t], redmax[1][t]);
    part[(size_t)s * NROWS + row0 + t] = m;
    part[(size_t)(8 + s) * NROWS + row0 + t] = M;
  }
}

// ---------------- 2-stage final reduce ----------------
__global__ __launch_bounds__(256) void tl_reduce_a(const float* __restrict__ part,
                                                   float* __restrict__ partial) {
  __shared__ float red[256];
  const int t = threadIdx.x;
  const int row = blockIdx.x * 256 + t;  // 32 blocks x 256 rows
  float ms = 1e30f, md = -1e30f;
#pragma unroll
  for (int s2 = 0; s2 < 8; ++s2) {
    ms = fminf(ms, part[(size_t)s2 * NROWS + row]);
    md = fmaxf(md, part[(size_t)(8 + s2) * NROWS + row]);
  }
  const float hp = fmaxf(1.0f - ms, 0.0f);
  const float hn = 1.0f - md;
  red[t] = fmaxf(MARGIN_F + hp - hn, 0.0f);
  __syncthreads();
  for (int off = 128; off > 0; off >>= 1) {
    if (t < off) red[t] += red[t + off];
    __syncthreads();
  }
  if (t == 0) partial[blockIdx.x] = red[0];
}

__global__ void tl_reduce_b(const float* __restrict__ partial,
                            float* __restrict__ out) {
  const int t = threadIdx.x;  // 64 threads
  float v = (t < 32) ? partial[t] : 0.f;
#pragma unroll
  for (int off = 1; off < 64; off <<= 1) v += __shfl_xor(v, off);
  if (t == 0) out[0] = v / (float)NROWS;
}

// ================= fallback (R2-style, proven): used if ws too small =========
#define FJSPLIT 4
#define FJRANGE (NROWS / FJSPLIT)
#define FBM 128
#define FBN 64
#define FNRB (NROWS / FBM)
#define FNT (FJRANGE / FBN)

__device__ __forceinline__ float bf16tof_fb(unsigned short h) {
  union { uint32_t u; float f; } v; v.u = ((uint32_t)h) << 16;
  return v.f;
}
__device__ __forceinline__ void cvt8_fb(const float4 a, const float4 b,
                                        u16x8* h, u16x8* l) {
  float f[8] = {a.x, a.y, a.z, a.w, b.x, b.y, b.z, b.w};
  u16x8 hh, ll;
#pragma unroll
  for (int i = 0; i < 8; ++i) {
    unsigned short hv = bf16rn(f[i]);
    hh[i] = hv;
    ll[i] = bf16rn(f[i] - bf16tof_fb(hv));
  }
  *h = hh; *l = ll;
}

__global__ __launch_bounds__(256, 1) void tl_partial_fb(
    const float* __restrict__ E, const int* __restrict__ labels,
    float* __restrict__ ws) {
  __shared__ unsigned short Ah[FBM * DIM];
  __shared__ unsigned short Al[FBM * DIM];
  __shared__ unsigned short Bhs[2][FBN * DIM];
  __shared__ unsigned short Bls[2][FBN * DIM];
  __shared__ float redmin[2][FBM];
  __shared__ float redmax[2][FBM];

  const int t = threadIdx.x;
  const int l = t & 63;
  const int wid = t >> 6;
  const int wr = wid >> 1, wc = wid & 1;
  const int bid = blockIdx.x;
  const int rb = bid & (FNRB - 1);
  const int s = bid >> 6;
  const int row0 = rb * FBM;
  const int jbase0 = s * FJRANGE;

  bool odd0 = true;
  for (int q = 1; q < 128; q += 2) odd0 = odd0 && (labels[q] == 0);
  const int lstride = odd0 ? 2 : 1;

  int rlab[16];
#pragma unroll
  for (int mi = 0; mi < 4; ++mi)
#pragma unroll
    for (int j = 0; j < 4; ++j)
      rlab[mi * 4 + j] =
          labels[(row0 + wr * 64 + mi * 16 + (l >> 4) * 4 + j) * lstride];

#pragma unroll
  for (int it = 0; it < 8; ++it) {
    int gidx = it * 256 + t;
    int row = gidx >> 4;
    int kg = gidx & 15;
    const float* p = &E[(size_t)(row0 + row) * DIM + kg * 8];
    float4 f0 = *(const float4*)p;
    float4 f1 = *(const float4*)(p + 4);
    u16x8 h, lo;
    cvt8_fb(f0, f1, &h, &lo);
    int off = row * DIM + (kg ^ (row & 7)) * 8;
    *(u16x8*)&Ah[off] = h;
    *(u16x8*)&Al[off] = lo;
  }

  float4 bre[8];
  auto loadB = [&](int jt) {
#pragma unroll
    for (int it = 0; it < 4; ++it) {
      int gidx = it * 256 + t;
      int row = gidx >> 4;
      int kg = gidx & 15;
      const float* p = &E[(size_t)(jbase0 + jt * FBN + row) * DIM + kg * 8];
      bre[2 * it] = *(const float4*)p;
      bre[2 * it + 1] = *(const float4*)(p + 4);
    }
  };
  auto writeB = [&](int buf) {
#pragma unroll
    for (int it = 0; it < 4; ++it) {
      int gidx = it * 256 + t;
      int row = gidx >> 4;
      int kg = gidx & 15;
      u16x8 h, lo;
      cvt8_fb(bre[2 * it], bre[2 * it + 1], &h, &lo);
      int off = row * DIM + (kg ^ (row & 7)) * 8;
      *(u16x8*)&Bhs[buf][off] = h;
      *(u16x8*)&Bls[buf][off] = lo;
    }
  };

  loadB(0);
  writeB(0);
  __syncthreads();

  float minS[16], maxD[16];
#pragma unroll
  for (int i = 0; i < 16; ++i) { minS[i] = 1e30f; maxD[i] = -1e30f; }

  for (int jt = 0; jt < FNT; ++jt) {
    const int buf = jt & 1;
    if (jt + 1 < FNT) loadB(jt + 1);

    f32x4 acc[4][2];
#pragma unroll
    for (int mi = 0; mi < 4; ++mi)
#pragma unroll
      for (int ni = 0; ni < 2; ++ni) acc[mi][ni] = (f32x4){0.f, 0.f, 0.f, 0.f};

#pragma unroll
    for (int ks = 0; ks < 4; ++ks) {
      const int kq = ks * 4 + (l >> 4);
      s16x8 ah[4], al4[4], bh2[2], bl2[2];
#pragma unroll
      for (int mi = 0; mi < 4; ++mi) {
        int row = wr * 64 + mi * 16 + (l & 15);
        int off = row * DIM + (kq ^ (row & 7)) * 8;
        ah[mi] = *(const s16x8*)&Ah[off];
        al4[mi] = *(const s16x8*)&Al[off];
      }
#pragma unroll
      for (int ni = 0; ni < 2; ++ni) {
        int row = wc * 32 + ni * 16 + (l & 15);
        int off = row * DIM + (kq ^ (row & 7)) * 8;
        bh2[ni] = *(const s16x8*)&Bhs[buf][off];
        bl2[ni] = *(const s16x8*)&Bls[buf][off];
      }
#pragma unroll
      for (int mi = 0; mi < 4; ++mi)
#pragma unroll
        for (int ni = 0; ni < 2; ++ni) {
          acc[mi][ni] = __builtin_amdgcn_mfma_f32_16x16x32_bf16(
              ah[mi], bh2[ni], acc[mi][ni], 0, 0, 0);
          acc[mi][ni] = __builtin_amdgcn_mfma_f32_16x16x32_bf16(
              ah[mi], bl2[ni], acc[mi][ni], 0, 0, 0);
          acc[mi][ni] = __builtin_amdgcn_mfma_f32_16x16x32_bf16(
              al4[mi], bh2[ni], acc[mi][ni], 0, 0, 0);
        }
    }

    int clab[2];
#pragma unroll
    for (int ni = 0; ni < 2; ++ni)
      clab[ni] =
          labels[(jbase0 + jt * FBN + wc * 32 + ni * 16 + (l & 15)) * lstride];
#pragma unroll
    for (int mi = 0; mi < 4; ++mi)
#pragma unroll
      for (int j = 0; j < 4; ++j) {
        const int idx = mi * 4 + j;
#pragma unroll
        for (int ni = 0; ni < 2; ++ni) {
          float d = acc[mi][ni][j];
          bool same = (clab[ni] == rlab[idx]);
          minS[idx] = (same && d < minS[idx]) ? d : minS[idx];
          maxD[idx] = (!same && d > maxD[idx]) ? d : maxD[idx];
        }
      }

    if (jt + 1 < FNT) writeB(buf ^ 1);
    __syncthreads();
  }

#pragma unroll
  for (int i = 0; i < 16; ++i) {
    float v0 = minS[i], v1 = maxD[i];
#pragma unroll
    for (int off = 1; off < 16; off <<= 1) {
      v0 = fminf(v0, __shfl_xor(v0, off));
      v1 = fmaxf(v1, __shfl_xor(v1, off));
    }
    minS[i] = v0; maxD[i] = v1;
  }
  if ((l & 15) == 0) {
#pragma unroll
    for (int mi = 0; mi < 4; ++mi)
#pragma unroll
      for (int j = 0; j < 4; ++j) {
        int row = wr * 64 + mi * 16 + (l >> 4) * 4 + j;
        redmin[wc][row] = minS[mi * 4 + j];
        redmax[wc][row] = maxD[mi * 4 + j];
      }
  }
  __syncthreads();
  if (t < FBM) {
    float m = fminf(redmin[0][t], redmin[1][t]);
    float M = fmaxf(redmax[0][t], redmax[1][t]);
    ws[s * NROWS + row0 + t] = m;
    ws[(FJSPLIT + s) * NROWS + row0 + t] = M;
  }
}

__global__ void tl_reduce_fb(const float* __restrict__ ws, float* __restrict__ out) {
  __shared__ float red[256];
  const int t = threadIdx.x;
  float sum = 0.f;
  for (int r = t; r < NROWS; r += 256) {
    float ms = 1e30f, md = -1e30f;
#pragma unroll
    for (int s2 = 0; s2 < FJSPLIT; ++s2) {
      ms = fminf(ms, ws[s2 * NROWS + r]);
      md = fmaxf(md, ws[(FJSPLIT + s2) * NROWS + r]);
    }
    const float hp = fmaxf(1.0f - ms, 0.0f);
    const float hn = 1.0f - md;
    sum += fmaxf(MARGIN_F + hp - hn, 0.0f);
  }
  red[t] = sum;
  __syncthreads();
  for (int off = 128; off > 0; off >>= 1) {
    if (t < off) red[t] += red[t + off];
    __syncthreads();
  }
  if (t == 0) out[0] = red[0] / (float)NROWS;
}

extern "C" void kernel_launch(void* const* d_in, const int* in_sizes, int n_in,
                              void* d_out, int out_size, void* d_ws, size_t ws_size,
                              hipStream_t stream) {
  const float* E = (const float*)d_in[0];
  const int* labels = (const int*)d_in[1];
  float* out = (float*)d_out;

  const size_t HALF = (size_t)NROWS * DIM;       // 1048576 elems
  const size_t partOff = HALF * 2;               // 2MB (Ehi bf16)
  const size_t need = partOff + (size_t)NROWS * 16 * 4 + 4096;

  if (ws_size >= need) {
    unsigned short* Ehi = (unsigned short*)d_ws;
    float* part = (float*)((char*)d_ws + partOff);
    float* partial = part + (size_t)NROWS * 16;
    hipLaunchKernelGGL(tl_split, dim3(512), dim3(256), 0, stream, E, Ehi);
    hipLaunchKernelGGL(tl_mfma, dim3(NRB2 * JSPLIT2), dim3(256), 0, stream,
                       Ehi, labels, part);
    hipLaunchKernelGGL(tl_reduce_a, dim3(32), dim3(256), 0, stream, part, partial);
    hipLaunchKernelGGL(tl_reduce_b, dim3(1), dim3(64), 0, stream, partial, out);
  } else {
    float* ws = (float*)d_ws;
    hipLaunchKernelGGL(tl_partial_fb, dim3(FNRB * FJSPLIT), dim3(256), 0, stream,
                       E, labels, ws);
    hipLaunchKernelGGL(tl_reduce_fb, dim3(1), dim3(256), 0, stream, ws, out);
  }
}